// Round 1
// baseline (774.754 us; speedup 1.0000x reference)
//
#include <hip/hip_runtime.h>

#define KDIM 1024
#define NDIM 4096
#define BM 128
#define BN 128
#define BK 32

typedef __attribute__((ext_vector_type(4))) float f32x4;
typedef __attribute__((ext_vector_type(8))) short s16x8;
typedef __attribute__((ext_vector_type(8))) unsigned short u16x8;

// fp32 -> bf16 bits, round-to-nearest-even (inputs are finite)
__device__ __forceinline__ unsigned short f2bf(float f) {
    union { float f; unsigned u; } v; v.f = f;
    unsigned r = v.u + 0x7FFFu + ((v.u >> 16) & 1u);
    return (unsigned short)(r >> 16);
}

// GEMM: Y[M=32768][4096] = Xbf16[M][1024] * (W*coeff)^T + bias*rowcoef
// A-side (x) and B-side (W) both reg-staged f32 -> cvt bf16 -> LDS.
// LDS layout: [kc = k/8][row][8 bf16] -> conflict-free ds_read_b128 frags.
__global__ __launch_bounds__(256, 2) void mlv2_gemm(
    const float* __restrict__ X,
    const float* __restrict__ wts,
    const float* __restrict__ W,
    const float* __restrict__ bias,
    float* __restrict__ Y)
{
    __shared__ unsigned short Alds[2][4][BM][8];
    __shared__ unsigned short Blds[2][4][BN][8];

    const int tid = (int)threadIdx.x;
    // XCD-aware bijective swizzle: 8192 blocks, 8 XCDs. Consecutive wg on one
    // XCD share the same m_tile (A-tile reuse in per-XCD L2).
    const int bid = (int)blockIdx.x;
    const int wg  = (bid & 7) * 1024 + (bid >> 3);
    const int n_tile = wg & 31;   // 32 n-tiles
    const int m_tile = wg >> 5;   // 256 m-tiles

    float w[9];
#pragma unroll
    for (int k = 0; k < 9; ++k) w[k] = wts[k];

    // ---- staging coords: thread t covers row (t>>1), cols (t&1)*16..+15 of the 128x32 tile
    const int srow = tid >> 1;
    const int scol = (tid & 1) << 4;
    const int kc0  = (tid & 1) << 1;         // first k-chunk this thread writes
    const float* xp = X + (size_t)(m_tile * BM + srow) * KDIM + scol;
    const float* wp = W + (size_t)(n_tile * BN + srow) * KDIM + scol;

    // B-side coeff: coeff(o, i) = rp[region(i)], region constant per K-step
    const int orow = n_tile * BN + srow;
    const float rp2 = (orow < 2048 ? w[6] : 0.f) + (orow < 3072 ? w[7] : 0.f) + w[8];
    const float rp1 = rp2 + (orow < 1536 ? w[3] : 0.f) + (orow < 2304 ? w[4] : 0.f)
                          + (orow < 3072 ? w[5] : 0.f);
    const float rp0 = rp1 + (orow < 1024 ? w[0] : 0.f) + (orow < 1536 ? w[1] : 0.f)
                          + (orow < 2048 ? w[2] : 0.f);

    // ---- compute coords: 4 waves as 2x2, each wave owns a 64x64 output tile
    const int lane  = tid & 63;
    const int wv    = tid >> 6;
    const int frow  = lane & 15;
    const int kcl   = lane >> 4;                 // k-chunk this lane reads
    const int arow0 = (wv >> 1) * 64 + frow;     // A-frag row base in tile
    const int brow0 = (wv & 1) * 64 + frow;      // B-frag row base in tile

    auto coef = [&](int t) -> float { return t < 16 ? rp0 : (t < 24 ? rp1 : rp2); };

    auto stage_load = [&](int t, f32x4 a[4], f32x4 b[4]) {
        const f32x4* xq = (const f32x4*)(xp + t * BK);
        const f32x4* wq = (const f32x4*)(wp + t * BK);
#pragma unroll
        for (int j = 0; j < 4; ++j) { a[j] = xq[j]; b[j] = wq[j]; }
    };
    auto stage_write = [&](int buf, const f32x4 a[4], const f32x4 b[4], float cf) {
        u16x8 va[2], vb[2];
#pragma unroll
        for (int j = 0; j < 4; ++j)
#pragma unroll
            for (int e = 0; e < 4; ++e) {
                const int idx = j * 4 + e;
                va[idx >> 3][idx & 7] = f2bf(a[j][e]);
                vb[idx >> 3][idx & 7] = f2bf(b[j][e] * cf);
            }
        *(u16x8*)&Alds[buf][kc0    ][srow][0] = va[0];
        *(u16x8*)&Alds[buf][kc0 + 1][srow][0] = va[1];
        *(u16x8*)&Blds[buf][kc0    ][srow][0] = vb[0];
        *(u16x8*)&Blds[buf][kc0 + 1][srow][0] = vb[1];
    };

    f32x4 acc[4][4];
#pragma unroll
    for (int i = 0; i < 4; ++i)
#pragma unroll
        for (int j = 0; j < 4; ++j) acc[i][j] = (f32x4){0.f, 0.f, 0.f, 0.f};

    // prologue: stage tile 0 into buf 0
    {
        f32x4 a[4], b[4];
        stage_load(0, a, b);
        stage_write(0, a, b, coef(0));
    }
    __syncthreads();

    const int NT = KDIM / BK;   // 32
    int cur = 0;
    for (int t = 0; t < NT; ++t) {
        f32x4 a[4], b[4];
        if (t + 1 < NT) stage_load(t + 1, a, b);   // issue early (hide under MFMA)

        s16x8 af[4], bf_[4];
#pragma unroll
        for (int i = 0; i < 4; ++i) {
            af[i]  = *(const s16x8*)&Alds[cur][kcl][arow0 + i * 16][0];
            bf_[i] = *(const s16x8*)&Blds[cur][kcl][brow0 + i * 16][0];
        }
#pragma unroll
        for (int i = 0; i < 4; ++i)
#pragma unroll
            for (int j = 0; j < 4; ++j)
                acc[i][j] = __builtin_amdgcn_mfma_f32_16x16x32_bf16(
                    af[i], bf_[j], acc[i][j], 0, 0, 0);

        if (t + 1 < NT) stage_write(cur ^ 1, a, b, coef(t + 1));  // write late
        __syncthreads();
        cur ^= 1;
    }

    // ---- epilogue: add b[n] * rowcoef(n), store
    const int gm0 = m_tile * BM + (wv >> 1) * 64 + kcl * 4;
    const int gn0 = n_tile * BN + (wv & 1) * 64 + frow;
#pragma unroll
    for (int j = 0; j < 4; ++j) {
        const int n = gn0 + j * 16;
        float rc = (n < 1024 ? w[0] : 0.f) + (n < 1536 ? w[1] : 0.f)
                 + (n < 2048 ? w[2] : 0.f) + (n < 1536 ? w[3] : 0.f)
                 + (n < 2304 ? w[4] : 0.f) + (n < 3072 ? w[5] : 0.f)
                 + (n < 2048 ? w[6] : 0.f) + (n < 3072 ? w[7] : 0.f) + w[8];
        const float bc = bias[n] * rc;
#pragma unroll
        for (int i = 0; i < 4; ++i) {
            float* yp = Y + (size_t)(gm0 + i * 16) * NDIM + n;
            yp[0 * NDIM] = acc[i][j][0] + bc;
            yp[1 * NDIM] = acc[i][j][1] + bc;
            yp[2 * NDIM] = acc[i][j][2] + bc;
            yp[3 * NDIM] = acc[i][j][3] + bc;
        }
    }
}

extern "C" void kernel_launch(void* const* d_in, const int* in_sizes, int n_in,
                              void* d_out, int out_size, void* d_ws, size_t ws_size,
                              hipStream_t stream) {
    const float* X    = (const float*)d_in[0];   // [8,4096,1024] f32
    const float* wts  = (const float*)d_in[1];   // [9] f32
    const float* W    = (const float*)d_in[2];   // [4096,1024] f32
    const float* bias = (const float*)d_in[3];   // [4096] f32
    float* Y = (float*)d_out;                    // [8,4096,4096] f32

    const int M = in_sizes[0] / KDIM;            // 32768
    const int grid = (M / BM) * (NDIM / BN);     // 8192
    mlv2_gemm<<<grid, 256, 0, stream>>>(X, wts, W, bias, Y);
}

// Round 2
// 629.328 us; speedup vs baseline: 1.2311x; 1.2311x over previous
//
#include <hip/hip_runtime.h>

#define KDIM 1024
#define NDIM 4096
#define BM 128
#define BN 128
#define BK 32

typedef __attribute__((ext_vector_type(4))) float f32x4;
typedef __attribute__((ext_vector_type(8))) short s16x8;
typedef __attribute__((ext_vector_type(8))) unsigned short u16x8;

__device__ __forceinline__ unsigned short f2bf(float f) {
    union { float f; unsigned u; } v; v.f = f;
    unsigned r = v.u + 0x7FFFu + ((v.u >> 16) & 1u);
    return (unsigned short)(r >> 16);
}

// async global->LDS, 16B per lane, LDS dest is wave-uniform base + lane*16
#define GLDS(gsrc, ldst)                                                        \
    __builtin_amdgcn_global_load_lds(                                           \
        (const __attribute__((address_space(1))) unsigned int*)(gsrc),          \
        (__attribute__((address_space(3))) unsigned int*)(ldst), 16, 0, 0)

// row-mix coefficient pieces for output row o (col regions 0:<512, 1:<768, 2:<1024)
__device__ __forceinline__ void row_coeffs(int o, const float* w,
                                           float& rp0, float& rp1, float& rp2) {
    rp2 = (o < 2048 ? w[6] : 0.f) + (o < 3072 ? w[7] : 0.f) + w[8];
    rp1 = rp2 + (o < 1536 ? w[3] : 0.f) + (o < 2304 ? w[4] : 0.f) + (o < 3072 ? w[5] : 0.f);
    rp0 = rp1 + (o < 1024 ? w[0] : 0.f) + (o < 1536 ? w[1] : 0.f) + (o < 2048 ? w[2] : 0.f);
}

// ---------------- pre-pass: X f32 -> bf16 ----------------
__global__ __launch_bounds__(256) void prep_x(const float* __restrict__ X,
                                              unsigned short* __restrict__ XB, int n8) {
    int i = blockIdx.x * blockDim.x + threadIdx.x;
    const int stride = gridDim.x * blockDim.x;
    for (; i < n8; i += stride) {
        const f32x4* p = (const f32x4*)(X + (size_t)i * 8);
        f32x4 a = p[0], b = p[1];
        u16x8 o;
        o[0] = f2bf(a[0]); o[1] = f2bf(a[1]); o[2] = f2bf(a[2]); o[3] = f2bf(a[3]);
        o[4] = f2bf(b[0]); o[5] = f2bf(b[1]); o[6] = f2bf(b[2]); o[7] = f2bf(b[3]);
        *(u16x8*)(XB + (size_t)i * 8) = o;
    }
}

// ---------------- pre-pass: W_mix = W * coeff -> bf16 ----------------
__global__ __launch_bounds__(256) void prep_w(const float* __restrict__ W,
                                              const float* __restrict__ wts,
                                              unsigned short* __restrict__ WB) {
    const int g = blockIdx.x * blockDim.x + threadIdx.x;   // group of 8 cols
    if (g >= NDIM * (KDIM / 8)) return;
    const int o = g >> 7, ig = g & 127;
    float w[9];
#pragma unroll
    for (int k = 0; k < 9; ++k) w[k] = wts[k];
    float rp0, rp1, rp2;
    row_coeffs(o, w, rp0, rp1, rp2);
    const float cf = ig < 64 ? rp0 : (ig < 96 ? rp1 : rp2);
    const f32x4* p = (const f32x4*)(W + (size_t)g * 8);
    f32x4 a = p[0], b = p[1];
    u16x8 ov;
    ov[0] = f2bf(a[0] * cf); ov[1] = f2bf(a[1] * cf); ov[2] = f2bf(a[2] * cf); ov[3] = f2bf(a[3] * cf);
    ov[4] = f2bf(b[0] * cf); ov[5] = f2bf(b[1] * cf); ov[6] = f2bf(b[2] * cf); ov[7] = f2bf(b[3] * cf);
    *(u16x8*)(WB + (size_t)g * 8) = ov;
}

// ---------------- main GEMM: m97 structure, global_load_lds, bf16 ----------------
__global__ __launch_bounds__(256, 3) void mlv2_gemm_v2(
    const unsigned short* __restrict__ XB,
    const unsigned short* __restrict__ WB,
    const float* __restrict__ wts,
    const float* __restrict__ bias,
    float* __restrict__ Y)
{
    __shared__ unsigned short Alds[2][4][BM][8];   // [buf][kc][row][8] bf16
    __shared__ unsigned short Blds[2][4][BN][8];

    const int tid = (int)threadIdx.x;
    const int bid = (int)blockIdx.x;
    // XCD-aware bijective swizzle (8192 % 8 == 0)
    const int wg  = (bid & 7) * 1024 + (bid >> 3);
    const int n_tile = wg & 31;
    const int m_tile = wg >> 5;
    const int m0 = m_tile * BM;
    const int n0 = n_tile * BN;

    const int lane = tid & 63;
    const int wv   = tid >> 6;

    // per-lane pre-swizzled global sources; LDS dest linear (m173 pattern).
    // chunk c covers LDS bytes [c*16, +16) of a buffer = [kc=c>>7][row=c&127][0..8)
    const unsigned short* srcA[2];
    const unsigned short* srcB[2];
    unsigned ldsoff[2];
#pragma unroll
    for (int q = 0; q < 2; ++q) {
        const int c   = (wv * 2 + q) * 64 + lane;
        const int kc  = c >> 7;
        const int row = c & 127;
        srcA[q] = XB + (size_t)(m0 + row) * KDIM + kc * 8;
        srcB[q] = WB + (size_t)(n0 + row) * KDIM + kc * 8;
        ldsoff[q] = (unsigned)((wv * 2 + q) * 512);   // ushort offset, wave-uniform
    }

    auto stage = [&](int buf, int t) {
        const int koff = t * BK;
#pragma unroll
        for (int q = 0; q < 2; ++q) {
            GLDS(srcA[q] + koff, &Alds[buf][0][0][0] + ldsoff[q]);
            GLDS(srcB[q] + koff, &Blds[buf][0][0][0] + ldsoff[q]);
        }
    };

    // compute coords: 4 waves as 2x2 -> 64x64 per wave
    const int frow  = lane & 15;
    const int kcl   = lane >> 4;
    const int arow0 = (wv >> 1) * 64 + frow;
    const int brow0 = (wv & 1) * 64 + frow;

    f32x4 acc[4][4];
#pragma unroll
    for (int i = 0; i < 4; ++i)
#pragma unroll
        for (int j = 0; j < 4; ++j) acc[i][j] = (f32x4){0.f, 0.f, 0.f, 0.f};

    stage(0, 0);
    __syncthreads();    // vmcnt(0) drained by compiler before barrier

    const int NT = KDIM / BK;   // 32
    int cur = 0;
    for (int t = 0; t < NT; ++t) {
        if (t + 1 < NT) stage(cur ^ 1, t + 1);   // prefetch next tile

        s16x8 af[4], bf_[4];
#pragma unroll
        for (int i = 0; i < 4; ++i) {
            af[i]  = *(const s16x8*)&Alds[cur][kcl][arow0 + i * 16][0];
            bf_[i] = *(const s16x8*)&Blds[cur][kcl][brow0 + i * 16][0];
        }
#pragma unroll
        for (int i = 0; i < 4; ++i)
#pragma unroll
            for (int j = 0; j < 4; ++j)
                acc[i][j] = __builtin_amdgcn_mfma_f32_16x16x32_bf16(
                    af[i], bf_[j], acc[i][j], 0, 0, 0);

        __syncthreads();
        cur ^= 1;
    }

    // epilogue: + bias[n] * rowcoef(n)
    float w[9];
#pragma unroll
    for (int k = 0; k < 9; ++k) w[k] = wts[k];
    const int gm0 = m0 + (wv >> 1) * 64 + kcl * 4;
    const int gn0 = n0 + (wv & 1) * 64 + frow;
#pragma unroll
    for (int j = 0; j < 4; ++j) {
        const int n = gn0 + j * 16;
        float rc = (n < 1024 ? w[0] : 0.f) + (n < 1536 ? w[1] : 0.f)
                 + (n < 2048 ? w[2] : 0.f) + (n < 1536 ? w[3] : 0.f)
                 + (n < 2304 ? w[4] : 0.f) + (n < 3072 ? w[5] : 0.f)
                 + (n < 2048 ? w[6] : 0.f) + (n < 3072 ? w[7] : 0.f) + w[8];
        const float bc = bias[n] * rc;
#pragma unroll
        for (int i = 0; i < 4; ++i) {
            float* yp = Y + (size_t)(gm0 + i * 16) * NDIM + n;
            yp[0 * NDIM] = acc[i][j][0] + bc;
            yp[1 * NDIM] = acc[i][j][1] + bc;
            yp[2 * NDIM] = acc[i][j][2] + bc;
            yp[3 * NDIM] = acc[i][j][3] + bc;
        }
    }
}

// ---------------- fallback (round-1 fused kernel, validated) ----------------
__global__ __launch_bounds__(256, 2) void mlv2_gemm_v1(
    const float* __restrict__ X, const float* __restrict__ wts,
    const float* __restrict__ W, const float* __restrict__ bias,
    float* __restrict__ Y)
{
    __shared__ unsigned short Alds[2][4][BM][8];
    __shared__ unsigned short Blds[2][4][BN][8];
    const int tid = (int)threadIdx.x;
    const int bid = (int)blockIdx.x;
    const int wg  = (bid & 7) * 1024 + (bid >> 3);
    const int n_tile = wg & 31;
    const int m_tile = wg >> 5;
    float w[9];
#pragma unroll
    for (int k = 0; k < 9; ++k) w[k] = wts[k];
    const int srow = tid >> 1;
    const int scol = (tid & 1) << 4;
    const int kc0  = (tid & 1) << 1;
    const float* xp = X + (size_t)(m_tile * BM + srow) * KDIM + scol;
    const float* wp = W + (size_t)(n_tile * BN + srow) * KDIM + scol;
    const int orow = n_tile * BN + srow;
    float rp0, rp1, rp2;
    row_coeffs(orow, w, rp0, rp1, rp2);
    const int lane = tid & 63, wv = tid >> 6;
    const int frow = lane & 15, kcl = lane >> 4;
    const int arow0 = (wv >> 1) * 64 + frow;
    const int brow0 = (wv & 1) * 64 + frow;
    auto coef = [&](int t) -> float { return t < 16 ? rp0 : (t < 24 ? rp1 : rp2); };
    auto stage_load = [&](int t, f32x4 a[4], f32x4 b[4]) {
        const f32x4* xq = (const f32x4*)(xp + t * BK);
        const f32x4* wq = (const f32x4*)(wp + t * BK);
#pragma unroll
        for (int j = 0; j < 4; ++j) { a[j] = xq[j]; b[j] = wq[j]; }
    };
    auto stage_write = [&](int buf, const f32x4 a[4], const f32x4 b[4], float cf) {
        u16x8 va[2], vb[2];
#pragma unroll
        for (int j = 0; j < 4; ++j)
#pragma unroll
            for (int e = 0; e < 4; ++e) {
                const int idx = j * 4 + e;
                va[idx >> 3][idx & 7] = f2bf(a[j][e]);
                vb[idx >> 3][idx & 7] = f2bf(b[j][e] * cf);
            }
        *(u16x8*)&Alds[buf][kc0    ][srow][0] = va[0];
        *(u16x8*)&Alds[buf][kc0 + 1][srow][0] = va[1];
        *(u16x8*)&Blds[buf][kc0    ][srow][0] = vb[0];
        *(u16x8*)&Blds[buf][kc0 + 1][srow][0] = vb[1];
    };
    f32x4 acc[4][4];
#pragma unroll
    for (int i = 0; i < 4; ++i)
#pragma unroll
        for (int j = 0; j < 4; ++j) acc[i][j] = (f32x4){0.f, 0.f, 0.f, 0.f};
    {
        f32x4 a[4], b[4];
        stage_load(0, a, b);
        stage_write(0, a, b, coef(0));
    }
    __syncthreads();
    const int NT = KDIM / BK;
    int cur = 0;
    for (int t = 0; t < NT; ++t) {
        f32x4 a[4], b[4];
        if (t + 1 < NT) stage_load(t + 1, a, b);
        s16x8 af[4], bf_[4];
#pragma unroll
        for (int i = 0; i < 4; ++i) {
            af[i]  = *(const s16x8*)&Alds[cur][kcl][arow0 + i * 16][0];
            bf_[i] = *(const s16x8*)&Blds[cur][kcl][brow0 + i * 16][0];
        }
#pragma unroll
        for (int i = 0; i < 4; ++i)
#pragma unroll
            for (int j = 0; j < 4; ++j)
                acc[i][j] = __builtin_amdgcn_mfma_f32_16x16x32_bf16(
                    af[i], bf_[j], acc[i][j], 0, 0, 0);
        if (t + 1 < NT) stage_write(cur ^ 1, a, b, coef(t + 1));
        __syncthreads();
        cur ^= 1;
    }
    const int gm0 = m_tile * BM + (wv >> 1) * 64 + kcl * 4;
    const int gn0 = n_tile * BN + (wv & 1) * 64 + frow;
#pragma unroll
    for (int j = 0; j < 4; ++j) {
        const int n = gn0 + j * 16;
        float rc = (n < 1024 ? w[0] : 0.f) + (n < 1536 ? w[1] : 0.f)
                 + (n < 2048 ? w[2] : 0.f) + (n < 1536 ? w[3] : 0.f)
                 + (n < 2304 ? w[4] : 0.f) + (n < 3072 ? w[5] : 0.f)
                 + (n < 2048 ? w[6] : 0.f) + (n < 3072 ? w[7] : 0.f) + w[8];
        const float bc = bias[n] * rc;
#pragma unroll
        for (int i = 0; i < 4; ++i) {
            float* yp = Y + (size_t)(gm0 + i * 16) * NDIM + n;
            yp[0 * NDIM] = acc[i][j][0] + bc;
            yp[1 * NDIM] = acc[i][j][1] + bc;
            yp[2 * NDIM] = acc[i][j][2] + bc;
            yp[3 * NDIM] = acc[i][j][3] + bc;
        }
    }
}

extern "C" void kernel_launch(void* const* d_in, const int* in_sizes, int n_in,
                              void* d_out, int out_size, void* d_ws, size_t ws_size,
                              hipStream_t stream) {
    const float* X    = (const float*)d_in[0];
    const float* wts  = (const float*)d_in[1];
    const float* W    = (const float*)d_in[2];
    const float* bias = (const float*)d_in[3];
    float* Y = (float*)d_out;

    const int M = in_sizes[0] / KDIM;            // 32768
    const int grid = (M / KDIM ? 0 : 0) + (M / BM) * (NDIM / BN);   // 8192

    const size_t xb_elems = (size_t)M * KDIM;           // 33,554,432
    const size_t wb_elems = (size_t)NDIM * KDIM;        //  4,194,304
    const size_t ws_needed = (xb_elems + wb_elems) * sizeof(unsigned short);

    if (ws_size >= ws_needed) {
        unsigned short* XB = (unsigned short*)d_ws;
        unsigned short* WB = XB + xb_elems;
        const int n8x = (int)(xb_elems / 8);
        prep_x<<<4096, 256, 0, stream>>>(X, XB, n8x);
        prep_w<<<(NDIM * (KDIM / 8)) / 256, 256, 0, stream>>>(W, wts, WB);
        mlv2_gemm_v2<<<grid, 256, 0, stream>>>(XB, WB, wts, bias, Y);
    } else {
        mlv2_gemm_v1<<<grid, 256, 0, stream>>>(X, wts, W, bias, Y);
    }
}

// Round 3
// 435.822 us; speedup vs baseline: 1.7777x; 1.4440x over previous
//
#include <hip/hip_runtime.h>

#define KDIM 1024
#define NDIM 4096

typedef __attribute__((ext_vector_type(4))) float f32x4;
typedef __attribute__((ext_vector_type(8))) short s16x8;
typedef __attribute__((ext_vector_type(8))) unsigned short u16x8;

__device__ __forceinline__ unsigned short f2bf(float f) {
    union { float f; unsigned u; } v; v.f = f;
    unsigned r = v.u + 0x7FFFu + ((v.u >> 16) & 1u);
    return (unsigned short)(r >> 16);
}

#define GLDS(gsrc, ldst)                                                        \
    __builtin_amdgcn_global_load_lds(                                           \
        (const __attribute__((address_space(1))) unsigned int*)(gsrc),          \
        (__attribute__((address_space(3))) unsigned int*)(ldst), 16, 0, 0)

#define SBAR() __builtin_amdgcn_s_barrier()
#define VMW(n) asm volatile("s_waitcnt vmcnt(" #n ")" ::: "memory")

__device__ __forceinline__ void row_coeffs(int o, const float* w,
                                           float& rp0, float& rp1, float& rp2) {
    rp2 = (o < 2048 ? w[6] : 0.f) + (o < 3072 ? w[7] : 0.f) + w[8];
    rp1 = rp2 + (o < 1536 ? w[3] : 0.f) + (o < 2304 ? w[4] : 0.f) + (o < 3072 ? w[5] : 0.f);
    rp0 = rp1 + (o < 1024 ? w[0] : 0.f) + (o < 1536 ? w[1] : 0.f) + (o < 2048 ? w[2] : 0.f);
}

__device__ __forceinline__ float row_bias_coef(int n, const float* w) {
    return (n < 1024 ? w[0] : 0.f) + (n < 1536 ? w[1] : 0.f)
         + (n < 2048 ? w[2] : 0.f) + (n < 1536 ? w[3] : 0.f)
         + (n < 2304 ? w[4] : 0.f) + (n < 3072 ? w[5] : 0.f)
         + (n < 2048 ? w[6] : 0.f) + (n < 3072 ? w[7] : 0.f) + w[8];
}

// ---------------- pre-pass: X f32 -> bf16 ----------------
__global__ __launch_bounds__(256) void prep_x(const float* __restrict__ X,
                                              unsigned short* __restrict__ XB, int n8) {
    int i = blockIdx.x * blockDim.x + threadIdx.x;
    const int stride = gridDim.x * blockDim.x;
    for (; i < n8; i += stride) {
        const f32x4* p = (const f32x4*)(X + (size_t)i * 8);
        f32x4 a = p[0], b = p[1];
        u16x8 o;
        o[0] = f2bf(a[0]); o[1] = f2bf(a[1]); o[2] = f2bf(a[2]); o[3] = f2bf(a[3]);
        o[4] = f2bf(b[0]); o[5] = f2bf(b[1]); o[6] = f2bf(b[2]); o[7] = f2bf(b[3]);
        *(u16x8*)(XB + (size_t)i * 8) = o;
    }
}

// ---------------- pre-pass: W_mix = W * coeff -> bf16 ----------------
__global__ __launch_bounds__(256) void prep_w(const float* __restrict__ W,
                                              const float* __restrict__ wts,
                                              unsigned short* __restrict__ WB) {
    const int g = blockIdx.x * blockDim.x + threadIdx.x;
    if (g >= NDIM * (KDIM / 8)) return;
    const int o = g >> 7, ig = g & 127;
    float w[9];
#pragma unroll
    for (int k = 0; k < 9; ++k) w[k] = wts[k];
    float rp0, rp1, rp2;
    row_coeffs(o, w, rp0, rp1, rp2);
    const float cf = ig < 64 ? rp0 : (ig < 96 ? rp1 : rp2);
    const f32x4* p = (const f32x4*)(W + (size_t)g * 8);
    f32x4 a = p[0], b = p[1];
    u16x8 ov;
    ov[0] = f2bf(a[0] * cf); ov[1] = f2bf(a[1] * cf); ov[2] = f2bf(a[2] * cf); ov[3] = f2bf(a[3] * cf);
    ov[4] = f2bf(b[0] * cf); ov[5] = f2bf(b[1] * cf); ov[6] = f2bf(b[2] * cf); ov[7] = f2bf(b[3] * cf);
    *(u16x8*)(WB + (size_t)g * 8) = ov;
}

// ---------------- main GEMM v3: 256x256 tile, BK=32, ring-3 LDS, counted vmcnt ----------------
// 8 waves = 2(M) x 4(N); per-wave output 128x64; acc[8][4] f32x4.
// LDS per buf: A 256x32 bf16 (16KB, swizzled) + B 256x32 (16KB) = 32KB; x3 = 96KB.
// Swizzle: 16B chunk c of row r stored at c ^ ((r>>1)&3)  (2-way reads = free).
// Staging: per group (1 K-tile), each wave issues 4 GLDS for kt+2 (A x2 @P0, B x2 @P1).
// End-of-group s_waitcnt vmcnt(4): kt+1 guaranteed landed, kt+2's 4 loads stay in flight.
__global__ __launch_bounds__(512, 2) void mlv2_gemm_v3(
    const unsigned short* __restrict__ XB,
    const unsigned short* __restrict__ WB,
    const float* __restrict__ wts,
    const float* __restrict__ bias,
    float* __restrict__ Y)
{
    __shared__ unsigned short LDS[3 * 16384];   // 96 KiB

    const int tid = (int)threadIdx.x;
    const int l   = tid & 63;
    const int w   = tid >> 6;      // wave 0..7
    const int wm  = w >> 2;        // 0..1
    const int wn  = w & 3;         // 0..3

    const int bid = (int)blockIdx.x;
    // XCD-aware bijective swizzle (2048 % 8 == 0)
    const int wg = (bid & 7) * 256 + (bid >> 3);
    const int n_tile = wg & 15;
    const int m_tile = wg >> 4;
    const int m0 = m_tile * 256;
    const int n0 = n_tile * 256;

    // ---- frag-read lane constants (swizzle collapses to a lane constant)
    const int rl = l & 15;
    const unsigned cw = (unsigned)((((l >> 4) ^ ((l >> 1) & 3)) * 8));
    unsigned offA[8], offB[4];
#pragma unroll
    for (int m = 0; m < 8; ++m)
        offA[m] = (unsigned)((wm * 128 + m * 16 + rl) * 32) + cw;
#pragma unroll
    for (int n = 0; n < 4; ++n)
        offB[n] = 8192u + (unsigned)((wn * 64 + n * 16 + rl) * 32) + cw;

    // ---- staging: wave w stages rows [32w, 32w+32) of A and of B per K-tile.
    // Linear LDS dest (wave-uniform base), inverse-swizzled per-lane global source.
    const int cg = (((l & 3) ^ ((l >> 3) & 3)) * 8);
    const int r0 = w * 32 + (l >> 2);
    const unsigned short* sA0 = XB + (size_t)(m0 + r0) * KDIM + cg;
    const unsigned short* sA1 = XB + (size_t)(m0 + r0 + 16) * KDIM + cg;
    const unsigned short* sB0 = WB + (size_t)(n0 + r0) * KDIM + cg;
    const unsigned short* sB1 = WB + (size_t)(n0 + r0 + 16) * KDIM + cg;
    const unsigned dA0 = (unsigned)(w * 1024);       // ushort offsets within a buf
    const unsigned dA1 = dA0 + 512;
    const unsigned dB0 = 8192u + dA0;
    const unsigned dB1 = 8192u + dA1;

    auto stageA = [&](int buf, int kt) {
        const int ko = kt * 32;
        GLDS(sA0 + ko, &LDS[buf * 16384 + dA0]);
        GLDS(sA1 + ko, &LDS[buf * 16384 + dA1]);
    };
    auto stageB = [&](int buf, int kt) {
        const int ko = kt * 32;
        GLDS(sB0 + ko, &LDS[buf * 16384 + dB0]);
        GLDS(sB1 + ko, &LDS[buf * 16384 + dB1]);
    };

    f32x4 acc[8][4];
#pragma unroll
    for (int m = 0; m < 8; ++m)
#pragma unroll
        for (int n = 0; n < 4; ++n) acc[m][n] = (f32x4){0.f, 0.f, 0.f, 0.f};

    // prologue: stage kt 0 and 1; wait for kt0 (leave kt1's 4 loads in flight)
    stageA(0, 0); stageB(0, 0);
    stageA(1, 1); stageB(1, 1);
    VMW(4);
    SBAR();

    const int NT = KDIM / 32;   // 32 K-tile groups
    int b0 = 0;
    for (int kt = 0; kt < NT; ++kt) {
        int buf2 = b0 + 2; if (buf2 >= 3) buf2 -= 3;
        const bool st = (kt + 2) < NT;
        const unsigned short* base = &LDS[b0 * 16384];

        s16x8 af[8], bfr[4];
        // ---- phase 0: stage A(kt+2) | read A m0-3 + B all | 16 MFMA
        if (st) stageA(buf2, kt + 2);
#pragma unroll
        for (int m = 0; m < 4; ++m) af[m] = *(const s16x8*)(base + offA[m]);
#pragma unroll
        for (int n = 0; n < 4; ++n) bfr[n] = *(const s16x8*)(base + offB[n]);
        SBAR();
        __builtin_amdgcn_s_setprio(1);
#pragma unroll
        for (int m = 0; m < 4; ++m)
#pragma unroll
            for (int n = 0; n < 4; ++n)
                acc[m][n] = __builtin_amdgcn_mfma_f32_16x16x32_bf16(
                    af[m], bfr[n], acc[m][n], 0, 0, 0);
        __builtin_amdgcn_s_setprio(0);
        SBAR();

        // ---- phase 1: stage B(kt+2) | read A m4-7 | 16 MFMA | counted vmcnt
        if (st) stageB(buf2, kt + 2);
#pragma unroll
        for (int m = 4; m < 8; ++m) af[m] = *(const s16x8*)(base + offA[m]);
        SBAR();
        __builtin_amdgcn_s_setprio(1);
#pragma unroll
        for (int m = 4; m < 8; ++m)
#pragma unroll
            for (int n = 0; n < 4; ++n)
                acc[m][n] = __builtin_amdgcn_mfma_f32_16x16x32_bf16(
                    af[m], bfr[n], acc[m][n], 0, 0, 0);
        __builtin_amdgcn_s_setprio(0);
        if (st) { VMW(4); } else { VMW(0); }
        SBAR();

        b0 = b0 + 1; if (b0 >= 3) b0 -= 3;
    }

    // ---- epilogue: + bias[n] * rowcoef(n), scalar stores
    float w9[9];
#pragma unroll
    for (int k = 0; k < 9; ++k) w9[k] = wts[k];
    const int gmb = m0 + wm * 128 + (l >> 4) * 4;
    const int gnb = n0 + wn * 64 + rl;
#pragma unroll
    for (int n = 0; n < 4; ++n) {
        const int gn = gnb + n * 16;
        const float bc = bias[gn] * row_bias_coef(gn, w9);
#pragma unroll
        for (int m = 0; m < 8; ++m) {
            float* yp = Y + (size_t)(gmb + m * 16) * NDIM + gn;
            yp[0 * NDIM] = acc[m][n][0] + bc;
            yp[1 * NDIM] = acc[m][n][1] + bc;
            yp[2 * NDIM] = acc[m][n][2] + bc;
            yp[3 * NDIM] = acc[m][n][3] + bc;
        }
    }
}

// ---------------- fallback (round-1 fused kernel, validated) ----------------
__global__ __launch_bounds__(256, 2) void mlv2_gemm_v1(
    const float* __restrict__ X, const float* __restrict__ wts,
    const float* __restrict__ W, const float* __restrict__ bias,
    float* __restrict__ Y)
{
    __shared__ unsigned short Alds[2][4][128][8];
    __shared__ unsigned short Blds[2][4][128][8];
    const int tid = (int)threadIdx.x;
    const int bid = (int)blockIdx.x;
    const int wg  = (bid & 7) * 1024 + (bid >> 3);
    const int n_tile = wg & 31;
    const int m_tile = wg >> 5;
    float w[9];
#pragma unroll
    for (int k = 0; k < 9; ++k) w[k] = wts[k];
    const int srow = tid >> 1;
    const int scol = (tid & 1) << 4;
    const int kc0  = (tid & 1) << 1;
    const float* xp = X + (size_t)(m_tile * 128 + srow) * KDIM + scol;
    const float* wp = W + (size_t)(n_tile * 128 + srow) * KDIM + scol;
    const int orow = n_tile * 128 + srow;
    float rp0, rp1, rp2;
    row_coeffs(orow, w, rp0, rp1, rp2);
    const int lane = tid & 63, wv = tid >> 6;
    const int frow = lane & 15, kcl = lane >> 4;
    const int arow0 = (wv >> 1) * 64 + frow;
    const int brow0 = (wv & 1) * 64 + frow;
    auto coef = [&](int t) -> float { return t < 16 ? rp0 : (t < 24 ? rp1 : rp2); };
    auto stage_load = [&](int t, f32x4 a[4], f32x4 b[4]) {
        const f32x4* xq = (const f32x4*)(xp + t * 32);
        const f32x4* wq = (const f32x4*)(wp + t * 32);
#pragma unroll
        for (int j = 0; j < 4; ++j) { a[j] = xq[j]; b[j] = wq[j]; }
    };
    auto stage_write = [&](int buf, const f32x4 a[4], const f32x4 b[4], float cf) {
        u16x8 va[2], vb[2];
#pragma unroll
        for (int j = 0; j < 4; ++j)
#pragma unroll
            for (int e = 0; e < 4; ++e) {
                const int idx = j * 4 + e;
                va[idx >> 3][idx & 7] = f2bf(a[j][e]);
                vb[idx >> 3][idx & 7] = f2bf(b[j][e] * cf);
            }
        *(u16x8*)&Alds[buf][kc0    ][srow][0] = va[0];
        *(u16x8*)&Alds[buf][kc0 + 1][srow][0] = va[1];
        *(u16x8*)&Blds[buf][kc0    ][srow][0] = vb[0];
        *(u16x8*)&Blds[buf][kc0 + 1][srow][0] = vb[1];
    };
    f32x4 acc[4][4];
#pragma unroll
    for (int i = 0; i < 4; ++i)
#pragma unroll
        for (int j = 0; j < 4; ++j) acc[i][j] = (f32x4){0.f, 0.f, 0.f, 0.f};
    {
        f32x4 a[4], b[4];
        stage_load(0, a, b);
        stage_write(0, a, b, coef(0));
    }
    __syncthreads();
    const int NT = KDIM / 32;
    int cur = 0;
    for (int t = 0; t < NT; ++t) {
        f32x4 a[4], b[4];
        if (t + 1 < NT) stage_load(t + 1, a, b);
        s16x8 af[4], bf_[4];
#pragma unroll
        for (int i = 0; i < 4; ++i) {
            af[i]  = *(const s16x8*)&Alds[cur][kcl][arow0 + i * 16][0];
            bf_[i] = *(const s16x8*)&Blds[cur][kcl][brow0 + i * 16][0];
        }
#pragma unroll
        for (int i = 0; i < 4; ++i)
#pragma unroll
            for (int j = 0; j < 4; ++j)
                acc[i][j] = __builtin_amdgcn_mfma_f32_16x16x32_bf16(
                    af[i], bf_[j], acc[i][j], 0, 0, 0);
        if (t + 1 < NT) stage_write(cur ^ 1, a, b, coef(t + 1));
        __syncthreads();
        cur ^= 1;
    }
    const int gm0 = m_tile * 128 + (wv >> 1) * 64 + kcl * 4;
    const int gn0 = n_tile * 128 + (wv & 1) * 64 + frow;
#pragma unroll
    for (int j = 0; j < 4; ++j) {
        const int n = gn0 + j * 16;
        const float bc = bias[n] * row_bias_coef(n, w);
#pragma unroll
        for (int i = 0; i < 4; ++i) {
            float* yp = Y + (size_t)(gm0 + i * 16) * NDIM + n;
            yp[0 * NDIM] = acc[i][j][0] + bc;
            yp[1 * NDIM] = acc[i][j][1] + bc;
            yp[2 * NDIM] = acc[i][j][2] + bc;
            yp[3 * NDIM] = acc[i][j][3] + bc;
        }
    }
}

extern "C" void kernel_launch(void* const* d_in, const int* in_sizes, int n_in,
                              void* d_out, int out_size, void* d_ws, size_t ws_size,
                              hipStream_t stream) {
    const float* X    = (const float*)d_in[0];
    const float* wts  = (const float*)d_in[1];
    const float* W    = (const float*)d_in[2];
    const float* bias = (const float*)d_in[3];
    float* Y = (float*)d_out;

    const int M = in_sizes[0] / KDIM;            // 32768

    const size_t xb_elems = (size_t)M * KDIM;
    const size_t wb_elems = (size_t)NDIM * KDIM;
    const size_t ws_needed = (xb_elems + wb_elems) * sizeof(unsigned short);

    if (ws_size >= ws_needed) {
        unsigned short* XB = (unsigned short*)d_ws;
        unsigned short* WB = XB + xb_elems;
        prep_x<<<4096, 256, 0, stream>>>(X, XB, (int)(xb_elems / 8));
        prep_w<<<(NDIM * (KDIM / 8)) / 256, 256, 0, stream>>>(W, wts, WB);
        const int grid = (M / 256) * (NDIM / 256);   // 2048
        mlv2_gemm_v3<<<grid, 512, 0, stream>>>(XB, WB, wts, bias, Y);
    } else {
        const int grid = (M / 128) * (NDIM / 128);
        mlv2_gemm_v1<<<grid, 256, 0, stream>>>(X, wts, W, bias, Y);
    }
}